// Round 6
// baseline (251.615 us; speedup 1.0000x reference)
//
#include <hip/hip_runtime.h>

#define D 64
#define D4 (D / 4)        // 16 float4 per row (fp32)
#define NPART 8           // chunk&7 ~ partition; blockIdx&7 ~ XCD (speed heuristic)
#define BSHIFT 7          // 128 nodes per bucket
#define BROWS 128
#define NB_MAX 1024       // supports n_nodes <= 131072
#define HG_HIST 512       // hist grid (blocks)
#define HG_APP  2048      // append grid (blocks) - full occupancy for latency hiding

typedef float  f32x4 __attribute__((ext_vector_type(4)));
typedef int    i32x4 __attribute__((ext_vector_type(4)));

__device__ __forceinline__ float elu1(float z) {
    return z > 0.0f ? z : expm1f(z);
}

// pack two fp32 -> bf16 pair (RNE), a in low 16, b in high 16
__device__ __forceinline__ unsigned int bfpair(float a, float b) {
    unsigned int ua = __float_as_uint(a);
    unsigned int ub = __float_as_uint(b);
    ua = (ua + 0x7FFFu + ((ua >> 16) & 1u)) >> 16;
    ub = (ub + 0x7FFFu + ((ub >> 16) & 1u)) & 0xFFFF0000u;
    return ub | ua;
}

// ---------- K1: emb16 = bf16(elu(x*w)); zero (p-major) bucket counters ----------
__global__ void emb_zero_counts_kernel(const float* __restrict__ x,
                                       const float* __restrict__ w,
                                       unsigned int* __restrict__ emb16,
                                       int* __restrict__ counts,
                                       int total4, int ncnt) {
    int i = blockIdx.x * blockDim.x + threadIdx.x;
    if (i < ncnt) counts[i] = 0;
    if (i >= total4) return;
    f32x4 xv = __builtin_nontemporal_load((const f32x4*)x + i);  // streamed once
    float4 wv = ((const float4*)w)[i & (D4 - 1)];
    float4 r;
    r.x = elu1(xv.x * wv.x);
    r.y = elu1(xv.y * wv.y);
    r.z = elu1(xv.z * wv.z);
    r.w = elu1(xv.w * wv.w);
    uint2 o;
    o.x = bfpair(r.x, r.y);
    o.y = bfpair(r.z, r.w);
    ((uint2*)emb16)[i] = o;
}

// ---------- K2: bucket histogram; partition p = chunk&7 (grid-independent) ----
__global__ void hist_kernel(const int* __restrict__ dst,
                            int* __restrict__ counts,   // [NPART][NB]
                            int n_edges, int NB) {
    __shared__ int lh[NB_MAX];
    const int tid = threadIdx.x;
    const int p  = blockIdx.x & (NPART - 1);
    const int jb = blockIdx.x >> 3;
    const int chunks = (n_edges + 255) >> 8;
    for (int b = tid; b < NB; b += blockDim.x) lh[b] = 0;
    __syncthreads();
    for (int c = 8 * jb + p; c < chunks; c += HG_HIST) {
        int e = (c << 8) + tid;
        if (e < n_edges) {
            int d = __builtin_nontemporal_load(dst + e);
            atomicAdd(&lh[d >> BSHIFT], 1);
        }
    }
    __syncthreads();
    for (int b = tid; b < NB; b += blockDim.x) {
        int v = lh[b];
        if (v) atomicAdd(&counts[p * NB + b], v);
    }
}

// ---------- K3: single-block scan over b-major (bucket,partition) counts ------
__global__ void scan_kernel(const int* __restrict__ counts,  // [NPART][NB]
                            int* __restrict__ offsets,       // [NB*8+1] b-major
                            int* __restrict__ cursor,        // [NPART][NB]
                            int NB) {
    __shared__ int wsum[16];
    const int NBP = NB * NPART;
    int tid = threadIdx.x;           // 1024 threads
    int lane = tid & 63, wid = tid >> 6;
    int v[8]; int s = 0;
    #pragma unroll
    for (int j = 0; j < 8; j++) {
        int idx = tid * 8 + j;
        int val = 0;
        if (idx < NBP) { int b = idx >> 3, p = idx & 7; val = counts[p * NB + b]; }
        v[j] = val; s += val;
    }
    int incl = s;
    #pragma unroll
    for (int off = 1; off < 64; off <<= 1) {
        int t = __shfl_up(incl, off, 64);
        if (lane >= off) incl += t;
    }
    if (lane == 63) wsum[wid] = incl;
    __syncthreads();
    if (tid == 0) {
        int r = 0;
        for (int k = 0; k < 16; k++) { int t = wsum[k]; wsum[k] = r; r += t; }
    }
    __syncthreads();
    int run = wsum[wid] + (incl - s);
    #pragma unroll
    for (int j = 0; j < 8; j++) {
        int idx = tid * 8 + j;
        if (idx < NBP) {
            int b = idx >> 3, p = idx & 7;
            offsets[idx] = run;
            cursor[p * NB + b] = run;
        }
        run += v[j];
    }
    if (tid == 1023) offsets[NBP] = run;
}

// ---------- K4: append at (p,bucket) tips; p = chunk&7; packed (dlocal<<18)|src
__global__ void append_kernel(const int* __restrict__ src,
                              const int* __restrict__ dst,
                              int* __restrict__ cursor,     // [NPART][NB]
                              int* __restrict__ sorted,
                              int n_edges, int NB) {
    const int tid = threadIdx.x;
    const int p  = blockIdx.x & (NPART - 1);
    const int jb = blockIdx.x >> 3;
    const int chunks = (n_edges + 255) >> 8;
    for (int c = 8 * jb + p; c < chunks; c += HG_APP) {
        int e = (c << 8) + tid;
        if (e < n_edges) {
            int d = __builtin_nontemporal_load(dst + e);
            int s = __builtin_nontemporal_load(src + e);
            int b = d >> BSHIFT;
            int pos = atomicAdd(&cursor[p * NB + b], 1);
            sorted[pos] = ((d & (BROWS - 1)) << 18) | s;   // cached store: tip lines
        }
    }
}

// ---------- K4b: fine counting-sort within each bucket; emit node offsets ------
__global__ void fine_sort_kernel(const int* __restrict__ sorted,
                                 const int* __restrict__ offsets,  // b-major
                                 int* __restrict__ sorted2,
                                 int* __restrict__ node_off,       // [n_nodes+1]
                                 int n_nodes, int NB) {
    __shared__ int rcount[BROWS];
    __shared__ int rcur[BROWS];
    const int b = blockIdx.x;
    const int tid = threadIdx.x;       // 256
    const int beg = offsets[b * 8];
    const int end = offsets[b * 8 + 8];
    if (tid < BROWS) rcount[tid] = 0;
    __syncthreads();
    for (int i = beg + tid; i < end; i += 256) {
        int pk = __builtin_nontemporal_load(sorted + i);
        atomicAdd(&rcount[(unsigned)pk >> 18], 1);
    }
    __syncthreads();
    if (tid == 0) {
        int run = beg;
        for (int r = 0; r < BROWS; r++) { rcur[r] = run; run += rcount[r]; }
    }
    __syncthreads();
    const int lo = b << BSHIFT;
    if (tid < BROWS && lo + tid < n_nodes) node_off[lo + tid] = rcur[tid];
    if (b == NB - 1 && tid == 0) node_off[n_nodes] = end;
    __syncthreads();
    for (int i = beg + tid; i < end; i += 256) {
        int pk = __builtin_nontemporal_load(sorted + i);
        int pos = atomicAdd(&rcur[(unsigned)pk >> 18], 1);
        sorted2[pos] = pk & 0x3FFFF;     // cached: 8KB L2-resident window
    }
}

// ---------- K5: wave per node; 8 groups x 8 lanes; bf16 rows; register accum ---
__global__ void gather_sum_kernel(const unsigned int* __restrict__ emb16,
                                  const int* __restrict__ sorted2,
                                  const int* __restrict__ node_off,
                                  float* __restrict__ out, int n_nodes) {
    int wave = (blockIdx.x * blockDim.x + threadIdx.x) >> 6;
    if (wave >= n_nodes) return;
    const int lane = threadIdx.x & 63;
    const int g = lane >> 3;          // 8 edge slots
    const int c = lane & 7;           // 8 int4-chunks per 128B row
    const int beg = node_off[wave], end = node_off[wave + 1];
    const int4* row = (const int4*)emb16;   // 8 int4 per row

    float acc[8] = {0.f, 0.f, 0.f, 0.f, 0.f, 0.f, 0.f, 0.f};
    int e = beg + g;
    for (; e + 8 < end; e += 16) {
        int s0 = __builtin_nontemporal_load(sorted2 + e);
        int s1 = __builtin_nontemporal_load(sorted2 + e + 8);
        int4 u0 = row[s0 * 8 + c];
        int4 u1 = row[s1 * 8 + c];
        acc[0] += __uint_as_float((unsigned)u0.x << 16) + __uint_as_float((unsigned)u1.x << 16);
        acc[1] += __uint_as_float(u0.x & 0xFFFF0000u)   + __uint_as_float(u1.x & 0xFFFF0000u);
        acc[2] += __uint_as_float((unsigned)u0.y << 16) + __uint_as_float((unsigned)u1.y << 16);
        acc[3] += __uint_as_float(u0.y & 0xFFFF0000u)   + __uint_as_float(u1.y & 0xFFFF0000u);
        acc[4] += __uint_as_float((unsigned)u0.z << 16) + __uint_as_float((unsigned)u1.z << 16);
        acc[5] += __uint_as_float(u0.z & 0xFFFF0000u)   + __uint_as_float(u1.z & 0xFFFF0000u);
        acc[6] += __uint_as_float((unsigned)u0.w << 16) + __uint_as_float((unsigned)u1.w << 16);
        acc[7] += __uint_as_float(u0.w & 0xFFFF0000u)   + __uint_as_float(u1.w & 0xFFFF0000u);
    }
    if (e < end) {
        int s0 = __builtin_nontemporal_load(sorted2 + e);
        int4 u0 = row[s0 * 8 + c];
        acc[0] += __uint_as_float((unsigned)u0.x << 16);
        acc[1] += __uint_as_float(u0.x & 0xFFFF0000u);
        acc[2] += __uint_as_float((unsigned)u0.y << 16);
        acc[3] += __uint_as_float(u0.y & 0xFFFF0000u);
        acc[4] += __uint_as_float((unsigned)u0.z << 16);
        acc[5] += __uint_as_float(u0.z & 0xFFFF0000u);
        acc[6] += __uint_as_float((unsigned)u0.w << 16);
        acc[7] += __uint_as_float(u0.w & 0xFFFF0000u);
    }
    #pragma unroll
    for (int off = 8; off <= 32; off <<= 1) {
        #pragma unroll
        for (int k = 0; k < 8; k++) acc[k] += __shfl_xor(acc[k], off, 64);
    }
    if (g == 0) {
        f32x4* out4 = (f32x4*)out;
        f32x4 o0 = {acc[0], acc[1], acc[2], acc[3]};
        f32x4 o1 = {acc[4], acc[5], acc[6], acc[7]};
        __builtin_nontemporal_store(o0, out4 + wave * D4 + c * 2);
        __builtin_nontemporal_store(o1, out4 + wave * D4 + c * 2 + 1);
    }
}

// ---------- Fallback: atomic scatter ----------
__global__ void zero_out_kernel(float* __restrict__ out, int total4) {
    int i = blockIdx.x * blockDim.x + threadIdx.x;
    if (i < total4) ((float4*)out)[i] = make_float4(0.f, 0.f, 0.f, 0.f);
}

__global__ void scatter_fused_kernel(const float* __restrict__ x,
                                     const float* __restrict__ w,
                                     const int* __restrict__ src,
                                     const int* __restrict__ dst,
                                     float* __restrict__ out, int n_edges) {
    int t = blockIdx.x * blockDim.x + threadIdx.x;
    int e = t >> 4;
    int c = t & 15;
    if (e >= n_edges) return;
    int s = src[e];
    int d = dst[e];
    float4 xv = ((const float4*)x)[s * D4 + c];
    float4 wv = ((const float4*)w)[c];
    float* o = out + d * D + c * 4;
    unsafeAtomicAdd(o + 0, elu1(xv.x * wv.x));
    unsafeAtomicAdd(o + 1, elu1(xv.y * wv.y));
    unsafeAtomicAdd(o + 2, elu1(xv.z * wv.z));
    unsafeAtomicAdd(o + 3, elu1(xv.w * wv.w));
}

extern "C" void kernel_launch(void* const* d_in, const int* in_sizes, int n_in,
                              void* d_out, int out_size, void* d_ws, size_t ws_size,
                              hipStream_t stream) {
    const float* x   = (const float*)d_in[0];   // [N, 64] fp32
    const float* w   = (const float*)d_in[1];   // [1, 64] fp32
    const int*   src = (const int*)d_in[2];     // [E] int32
    const int*   dst = (const int*)d_in[3];     // [E] int32
    float* out = (float*)d_out;

    const int n_nodes = in_sizes[0] / D;
    const int n_edges = in_sizes[2];
    const int total4  = n_nodes * D4;
    const int block = 256;

    const int NB = (n_nodes + BROWS - 1) >> BSHIFT;
    auto align16 = [](size_t v) { return (v + 15) & ~size_t(15); };
    const size_t emb_b     = align16((size_t)n_nodes * D * 2);           // bf16
    const size_t sorted_b  = align16((size_t)n_edges * sizeof(int));
    const size_t sorted2_b = sorted_b;
    const size_t counts_b  = align16((size_t)NB * NPART * sizeof(int));
    const size_t cursor_b  = counts_b;
    const size_t offsets_b = align16(((size_t)NB * NPART + 1) * sizeof(int));
    const size_t nodeoff_b = align16((size_t)(n_nodes + 1) * sizeof(int));
    const size_t need = emb_b + sorted_b + sorted2_b + counts_b + cursor_b +
                        offsets_b + nodeoff_b;

    if (ws_size >= need && NB <= NB_MAX && n_nodes <= (1 << 18)) {
        char* p = (char*)d_ws;
        unsigned int* emb16 = (unsigned int*)p;  p += emb_b;
        int* sorted   = (int*)p;  p += sorted_b;
        int* sorted2  = (int*)p;  p += sorted2_b;
        int* counts   = (int*)p;  p += counts_b;
        int* cursor   = (int*)p;  p += cursor_b;
        int* offsets  = (int*)p;  p += offsets_b;
        int* node_off = (int*)p;

        emb_zero_counts_kernel<<<(total4 + block - 1) / block, block, 0, stream>>>(
            x, w, emb16, counts, total4, NB * NPART);
        hist_kernel<<<HG_HIST, block, 0, stream>>>(dst, counts, n_edges, NB);
        scan_kernel<<<1, 1024, 0, stream>>>(counts, offsets, cursor, NB);
        append_kernel<<<HG_APP, block, 0, stream>>>(src, dst, cursor, sorted,
                                                    n_edges, NB);
        fine_sort_kernel<<<NB, block, 0, stream>>>(sorted, offsets, sorted2,
                                                   node_off, n_nodes, NB);
        const int wave_blocks = (n_nodes * 64 + block - 1) / block;
        gather_sum_kernel<<<wave_blocks, block, 0, stream>>>(
            emb16, sorted2, node_off, out, n_nodes);
    } else {
        zero_out_kernel<<<(total4 + block - 1) / block, block, 0, stream>>>(out, total4);
        const int nt = n_edges * 16;
        scatter_fused_kernel<<<(nt + block - 1) / block, block, 0, stream>>>(
            x, w, src, dst, out, n_edges);
    }
}

// Round 7
// 230.665 us; speedup vs baseline: 1.0908x; 1.0908x over previous
//
#include <hip/hip_runtime.h>

#define D 64
#define D4 (D / 4)         // 16 float4 per fp32 row
#define SBSHIFT 9          // 512 nodes per super-bucket
#define SBROWS 512
#define CHUNK_E 8192       // edges per chunk_sort block
#define SLOT 80            // padded entries per (chunk, sb) slot (mean ~42, +6 sigma)
#define STAGE_CAP 8704     // fine_sort staging entries (mean ~8163, +6 sigma)
#define OVCAP 65536        // overflow list capacity (entries)

typedef float f32x4 __attribute__((ext_vector_type(4)));

__device__ __forceinline__ float elu1(float z) {
    return z > 0.0f ? z : expm1f(z);
}

// pack two fp32 -> bf16 pair (RNE), a in low 16, b in high 16
__device__ __forceinline__ unsigned int bfpair(float a, float b) {
    unsigned int ua = __float_as_uint(a);
    unsigned int ub = __float_as_uint(b);
    ua = (ua + 0x7FFFu + ((ua >> 16) & 1u)) >> 16;
    ub = (ub + 0x7FFFu + ((ub >> 16) & 1u)) & 0xFFFF0000u;
    return ub | ua;
}

// ---------- K1: emb16 = bf16(elu(x*w)); zero overflow counter ----------
__global__ void emb_kernel(const float* __restrict__ x,
                           const float* __restrict__ w,
                           unsigned int* __restrict__ emb16,
                           int* __restrict__ ov_cnt,
                           int total4) {
    int i = blockIdx.x * blockDim.x + threadIdx.x;
    if (i == 0) *ov_cnt = 0;
    if (i >= total4) return;
    f32x4 xv = __builtin_nontemporal_load((const f32x4*)x + i);
    float4 wv = ((const float4*)w)[i & (D4 - 1)];
    float4 r;
    r.x = elu1(xv.x * wv.x);
    r.y = elu1(xv.y * wv.y);
    r.z = elu1(xv.z * wv.z);
    r.w = elu1(xv.w * wv.w);
    uint2 o;
    o.x = bfpair(r.x, r.y);
    o.y = bfpair(r.z, r.w);
    ((uint2*)emb16)[i] = o;
}

// ---------- K2: per-chunk LDS bucket sort -> deterministic padded slots ------
// No per-edge global atomics. Scattered writes confined to LDS. Global writes
// are contiguous runs into this block's own 62KB slot region.
__global__ __launch_bounds__(512) void chunk_sort_kernel(
        const int* __restrict__ src, const int* __restrict__ dst,
        int* __restrict__ slots,        // [NCH][NSB][SLOT]
        int* __restrict__ runcount,     // [NCH][NSB]
        int* __restrict__ ov_buf, int* __restrict__ ov_cnt,
        int n_edges, int NSB) {
    __shared__ int hist[256], base[256], cur[256];
    __shared__ int wsum[4];
    __shared__ int stage[CHUNK_E];      // 32 KB
    const int tid = threadIdx.x;
    const int c0  = blockIdx.x * CHUNK_E;
    const int kn  = min(CHUNK_E, n_edges - c0);

    if (tid < 256) hist[tid] = 0;
    __syncthreads();
    // pass 1: histogram by super-bucket
    for (int k = tid; k < kn; k += 512) {
        int d = dst[c0 + k];
        atomicAdd(&hist[d >> SBSHIFT], 1);
    }
    __syncthreads();
    // exclusive scan of hist[0..256) using waves 0..3
    int h = 0, incl = 0;
    if (tid < 256) {
        h = hist[tid];
        incl = h;
        #pragma unroll
        for (int off = 1; off < 64; off <<= 1) {
            int t = __shfl_up(incl, off, 64);
            if ((tid & 63) >= off) incl += t;
        }
        if ((tid & 63) == 63) wsum[tid >> 6] = incl;
    }
    __syncthreads();
    if (tid < 256) {
        int pre = 0;
        for (int k = 0; k < (tid >> 6); k++) pre += wsum[k];
        int e = pre + incl - h;
        base[tid] = e;
        cur[tid]  = e;
    }
    __syncthreads();
    // pass 2: re-read edges (L2-hot, same CU), scatter into LDS stage
    for (int k = tid; k < kn; k += 512) {
        int d = dst[c0 + k];
        int s = src[c0 + k];
        int pl = ((d & (SBROWS - 1)) << 17) | s;
        int pos = atomicAdd(&cur[d >> SBSHIFT], 1);
        stage[pos] = pl;
    }
    __syncthreads();
    // flush: one wave per super-bucket run; contiguous global writes
    const int wid = tid >> 6, lane = tid & 63;
    const size_t srow = (size_t)blockIdx.x * NSB;
    for (int r = wid; r < NSB; r += 8) {
        int cnt = hist[r];
        int b   = base[r];
        int binned = min(cnt, SLOT);
        size_t gb = (srow + r) * SLOT;
        for (int j = lane; j < binned; j += 64)
            slots[gb + j] = stage[b + j];
        if (lane == 0) runcount[srow + r] = binned;
        for (int j = SLOT + lane; j < cnt; j += 64) {   // rare overflow
            int pl = stage[b + j];
            int pos = atomicAdd(ov_cnt, 1);
            if (pos < OVCAP) {
                ov_buf[2 * pos]     = (r << SBSHIFT) | ((unsigned)pl >> 17);
                ov_buf[2 * pos + 1] = pl & 0x1FFFF;
            }
        }
    }
}

// ---------- K3: per-sb totals + exclusive scan -> sb_base ----------
__global__ void sb_scan_kernel(const int* __restrict__ runcount,
                               int* __restrict__ sb_base,
                               int* __restrict__ node_off,
                               int NSB, int NCH, int n_nodes) {
    __shared__ int wsum[4];
    const int tid = threadIdx.x;   // 256
    int tot = 0;
    for (int c = 0; c < NCH; c++)
        if (tid < NSB) tot += runcount[(size_t)c * NSB + tid];
    int incl = tot;
    #pragma unroll
    for (int off = 1; off < 64; off <<= 1) {
        int t = __shfl_up(incl, off, 64);
        if ((tid & 63) >= off) incl += t;
    }
    if ((tid & 63) == 63) wsum[tid >> 6] = incl;
    __syncthreads();
    int pre = 0;
    for (int k = 0; k < (tid >> 6); k++) pre += wsum[k];
    if (tid < NSB) sb_base[tid] = pre + incl - tot;
    if (tid == 0) {
        int g = wsum[0] + wsum[1] + wsum[2] + wsum[3];
        sb_base[NSB] = g;
        node_off[n_nodes] = g;
    }
}

// ---------- K4: per-sb LDS counting sort -> sorted2 (coalesced) + node_off ---
__global__ __launch_bounds__(256) void fine_sort_kernel(
        const int* __restrict__ slots,
        const int* __restrict__ runcount,
        const int* __restrict__ sb_base,
        int* __restrict__ sorted2,
        int* __restrict__ node_off,
        int n_nodes, int NSB, int NCH) {
    __shared__ int rc[256];
    __shared__ int counts[SBROWS], cur[SBROWS];
    __shared__ int wsum[4];
    __shared__ int stage_out[STAGE_CAP];   // 34.8 KB
    const int s = blockIdx.x;
    const int tid = threadIdx.x;           // 256
    const int wid = tid >> 6, lane = tid & 63;

    rc[tid] = (tid < NCH) ? runcount[(size_t)tid * NSB + s] : 0;
    for (int i = tid; i < SBROWS; i += 256) counts[i] = 0;
    __syncthreads();
    // total T for this sb
    int rsum = rc[tid];
    #pragma unroll
    for (int off = 1; off < 64; off <<= 1) rsum += __shfl_xor(rsum, off, 64);
    if (lane == 0) wsum[wid] = rsum;
    __syncthreads();
    const int T = wsum[0] + wsum[1] + wsum[2] + wsum[3];
    const bool fast = (T <= STAGE_CAP);
    // phase 1: histogram by local node (read runs; they land in local L2)
    for (int c = wid; c < NCH; c += 4) {
        int n = rc[c];
        size_t gb = ((size_t)c * NSB + s) * SLOT;
        for (int j = lane; j < n; j += 64)
            atomicAdd(&counts[((unsigned)slots[gb + j]) >> 17], 1);
    }
    __syncthreads();
    // phase 2: exclusive scan of counts[512] (2 elements/thread)
    int c0v = counts[2 * tid], c1v = counts[2 * tid + 1];
    int pair = c0v + c1v;
    int incl = pair;
    #pragma unroll
    for (int off = 1; off < 64; off <<= 1) {
        int t = __shfl_up(incl, off, 64);
        if ((tid & 63) >= off) incl += t;
    }
    if ((tid & 63) == 63) wsum[tid >> 6] = incl;
    __syncthreads();
    int pre = 0;
    for (int k = 0; k < (tid >> 6); k++) pre += wsum[k];
    const int sbb = sb_base[s];
    int e0 = pre + incl - pair;
    int e1 = e0 + c0v;
    cur[2 * tid]     = fast ? e0 : sbb + e0;
    cur[2 * tid + 1] = fast ? e1 : sbb + e1;
    int g0 = (s << SBSHIFT) + 2 * tid;
    if (g0 < n_nodes)     node_off[g0]     = sbb + e0;
    if (g0 + 1 < n_nodes) node_off[g0 + 1] = sbb + e1;
    __syncthreads();
    // phase 3: scatter (LDS stage fast path; direct global on rare huge sb)
    for (int c = wid; c < NCH; c += 4) {
        int n = rc[c];
        size_t gb = ((size_t)c * NSB + s) * SLOT;
        for (int j = lane; j < n; j += 64) {
            int pl = slots[gb + j];
            int r = ((unsigned)pl) >> 17;
            int pos = atomicAdd(&cur[r], 1);
            if (fast) stage_out[pos] = pl & 0x1FFFF;
            else      sorted2[pos]   = pl & 0x1FFFF;
        }
    }
    __syncthreads();
    // phase 4: coalesced flush
    if (fast) {
        for (int i = tid; i < T; i += 256)
            sorted2[sbb + i] = stage_out[i];
    }
}

// ---------- K5: wave per node; 8 groups x 8 lanes; bf16 rows; register accum --
__global__ void gather_sum_kernel(const unsigned int* __restrict__ emb16,
                                  const int* __restrict__ sorted2,
                                  const int* __restrict__ node_off,
                                  float* __restrict__ out, int n_nodes) {
    int wave = (blockIdx.x * blockDim.x + threadIdx.x) >> 6;
    if (wave >= n_nodes) return;
    const int lane = threadIdx.x & 63;
    const int g = lane >> 3;          // 8 edge slots
    const int c = lane & 7;           // 8 int4-chunks per 128B row
    const int beg = node_off[wave], end = node_off[wave + 1];
    const int4* row = (const int4*)emb16;   // 8 int4 per row

    float acc[8] = {0.f, 0.f, 0.f, 0.f, 0.f, 0.f, 0.f, 0.f};
    int e = beg + g;
    for (; e + 8 < end; e += 16) {
        int s0 = __builtin_nontemporal_load(sorted2 + e);
        int s1 = __builtin_nontemporal_load(sorted2 + e + 8);
        int4 u0 = row[s0 * 8 + c];
        int4 u1 = row[s1 * 8 + c];
        acc[0] += __uint_as_float((unsigned)u0.x << 16) + __uint_as_float((unsigned)u1.x << 16);
        acc[1] += __uint_as_float(u0.x & 0xFFFF0000u)   + __uint_as_float(u1.x & 0xFFFF0000u);
        acc[2] += __uint_as_float((unsigned)u0.y << 16) + __uint_as_float((unsigned)u1.y << 16);
        acc[3] += __uint_as_float(u0.y & 0xFFFF0000u)   + __uint_as_float(u1.y & 0xFFFF0000u);
        acc[4] += __uint_as_float((unsigned)u0.z << 16) + __uint_as_float((unsigned)u1.z << 16);
        acc[5] += __uint_as_float(u0.z & 0xFFFF0000u)   + __uint_as_float(u1.z & 0xFFFF0000u);
        acc[6] += __uint_as_float((unsigned)u0.w << 16) + __uint_as_float((unsigned)u1.w << 16);
        acc[7] += __uint_as_float(u0.w & 0xFFFF0000u)   + __uint_as_float(u1.w & 0xFFFF0000u);
    }
    if (e < end) {
        int s0 = __builtin_nontemporal_load(sorted2 + e);
        int4 u0 = row[s0 * 8 + c];
        acc[0] += __uint_as_float((unsigned)u0.x << 16);
        acc[1] += __uint_as_float(u0.x & 0xFFFF0000u);
        acc[2] += __uint_as_float((unsigned)u0.y << 16);
        acc[3] += __uint_as_float(u0.y & 0xFFFF0000u);
        acc[4] += __uint_as_float((unsigned)u0.z << 16);
        acc[5] += __uint_as_float(u0.z & 0xFFFF0000u);
        acc[6] += __uint_as_float((unsigned)u0.w << 16);
        acc[7] += __uint_as_float(u0.w & 0xFFFF0000u);
    }
    #pragma unroll
    for (int off = 8; off <= 32; off <<= 1) {
        #pragma unroll
        for (int k = 0; k < 8; k++) acc[k] += __shfl_xor(acc[k], off, 64);
    }
    if (g == 0) {
        f32x4* out4 = (f32x4*)out;
        f32x4 o0 = {acc[0], acc[1], acc[2], acc[3]};
        f32x4 o1 = {acc[4], acc[5], acc[6], acc[7]};
        __builtin_nontemporal_store(o0, out4 + wave * D4 + c * 2);
        __builtin_nontemporal_store(o1, out4 + wave * D4 + c * 2 + 1);
    }
}

// ---------- K6: apply overflow entries (normally zero) ----------
__global__ void overflow_apply_kernel(const float* __restrict__ x,
                                      const float* __restrict__ w,
                                      const int* __restrict__ ov_buf,
                                      const int* __restrict__ ov_cnt,
                                      float* __restrict__ out) {
    int n = *ov_cnt;
    if (n > OVCAP) n = OVCAP;
    for (int i = blockIdx.x * blockDim.x + threadIdx.x; i < n;
         i += gridDim.x * blockDim.x) {
        int d = ov_buf[2 * i];
        int s = ov_buf[2 * i + 1];
        const float4* x4 = (const float4*)x;
        const float4* w4 = (const float4*)w;
        for (int c = 0; c < D4; c++) {
            float4 xv = x4[s * D4 + c];
            float4 wv = w4[c];
            float* o = out + (size_t)d * D + c * 4;
            unsafeAtomicAdd(o + 0, elu1(xv.x * wv.x));
            unsafeAtomicAdd(o + 1, elu1(xv.y * wv.y));
            unsafeAtomicAdd(o + 2, elu1(xv.z * wv.z));
            unsafeAtomicAdd(o + 3, elu1(xv.w * wv.w));
        }
    }
}

// ---------- Fallback: atomic scatter ----------
__global__ void zero_out_kernel(float* __restrict__ out, int total4) {
    int i = blockIdx.x * blockDim.x + threadIdx.x;
    if (i < total4) ((float4*)out)[i] = make_float4(0.f, 0.f, 0.f, 0.f);
}

__global__ void scatter_fused_kernel(const float* __restrict__ x,
                                     const float* __restrict__ w,
                                     const int* __restrict__ src,
                                     const int* __restrict__ dst,
                                     float* __restrict__ out, int n_edges) {
    int t = blockIdx.x * blockDim.x + threadIdx.x;
    int e = t >> 4;
    int c = t & 15;
    if (e >= n_edges) return;
    int s = src[e];
    int d = dst[e];
    float4 xv = ((const float4*)x)[s * D4 + c];
    float4 wv = ((const float4*)w)[c];
    float* o = out + d * D + c * 4;
    unsafeAtomicAdd(o + 0, elu1(xv.x * wv.x));
    unsafeAtomicAdd(o + 1, elu1(xv.y * wv.y));
    unsafeAtomicAdd(o + 2, elu1(xv.z * wv.z));
    unsafeAtomicAdd(o + 3, elu1(xv.w * wv.w));
}

extern "C" void kernel_launch(void* const* d_in, const int* in_sizes, int n_in,
                              void* d_out, int out_size, void* d_ws, size_t ws_size,
                              hipStream_t stream) {
    const float* x   = (const float*)d_in[0];   // [N, 64] fp32
    const float* w   = (const float*)d_in[1];   // [1, 64] fp32
    const int*   src = (const int*)d_in[2];     // [E] int32
    const int*   dst = (const int*)d_in[3];     // [E] int32
    float* out = (float*)d_out;

    const int n_nodes = in_sizes[0] / D;
    const int n_edges = in_sizes[2];
    const int total4  = n_nodes * D4;
    const int block = 256;

    const int NSB = (n_nodes + SBROWS - 1) >> SBSHIFT;
    const int NCH = (n_edges + CHUNK_E - 1) / CHUNK_E;

    auto align16 = [](size_t v) { return (v + 15) & ~size_t(15); };
    const size_t emb_b      = align16((size_t)n_nodes * D * 2);          // bf16
    const size_t slots_b    = align16((size_t)NCH * NSB * SLOT * 4);
    const size_t runcount_b = align16((size_t)NCH * NSB * 4);
    const size_t sbbase_b   = align16((size_t)(NSB + 1) * 4);
    const size_t sorted2_b  = align16((size_t)n_edges * 4);
    const size_t nodeoff_b  = align16((size_t)(n_nodes + 1) * 4);
    const size_t ov_b       = align16((size_t)OVCAP * 8);
    const size_t ovcnt_b    = 16;
    const size_t need = emb_b + slots_b + runcount_b + sbbase_b +
                        sorted2_b + nodeoff_b + ov_b + ovcnt_b;

    if (ws_size >= need && n_nodes <= 131072 && NSB <= 256 && NCH <= 256) {
        char* p = (char*)d_ws;
        unsigned int* emb16 = (unsigned int*)p;  p += emb_b;
        int* slots    = (int*)p;  p += slots_b;
        int* runcount = (int*)p;  p += runcount_b;
        int* sb_base  = (int*)p;  p += sbbase_b;
        int* sorted2  = (int*)p;  p += sorted2_b;
        int* node_off = (int*)p;  p += nodeoff_b;
        int* ov_buf   = (int*)p;  p += ov_b;
        int* ov_cnt   = (int*)p;

        emb_kernel<<<(total4 + block - 1) / block, block, 0, stream>>>(
            x, w, emb16, ov_cnt, total4);
        chunk_sort_kernel<<<NCH, 512, 0, stream>>>(
            src, dst, slots, runcount, ov_buf, ov_cnt, n_edges, NSB);
        sb_scan_kernel<<<1, 256, 0, stream>>>(
            runcount, sb_base, node_off, NSB, NCH, n_nodes);
        fine_sort_kernel<<<NSB, 256, 0, stream>>>(
            slots, runcount, sb_base, sorted2, node_off, n_nodes, NSB, NCH);
        const int wave_blocks = (n_nodes * 64 + block - 1) / block;
        gather_sum_kernel<<<wave_blocks, block, 0, stream>>>(
            emb16, sorted2, node_off, out, n_nodes);
        overflow_apply_kernel<<<32, block, 0, stream>>>(
            x, w, ov_buf, ov_cnt, out);
    } else {
        zero_out_kernel<<<(total4 + block - 1) / block, block, 0, stream>>>(out, total4);
        const int nt = n_edges * 16;
        scatter_fused_kernel<<<(nt + block - 1) / block, block, 0, stream>>>(
            x, w, src, dst, out, n_edges);
    }
}

// Round 8
// 187.491 us; speedup vs baseline: 1.3420x; 1.2303x over previous
//
#include <hip/hip_runtime.h>

#define D 64
#define D4 (D / 4)         // 16 float4 per fp32 row
#define SBSHIFT 9          // 512 nodes per super-bucket
#define SBROWS 512
#define CHUNK_E 8192       // edges per chunk_sort block
#define SLOT 80            // padded entries per (chunk, sb) slot (mean ~42, +6 sigma)
#define STAGE_CAP 8704     // fine_sort staging entries (mean ~8163, +6 sigma)
#define OVCAP 65536        // overflow list capacity (entries)

typedef float f32x4 __attribute__((ext_vector_type(4)));

__device__ __forceinline__ float elu1(float z) {
    return z > 0.0f ? z : expm1f(z);
}

// pack two fp32 -> bf16 pair (RNE), a in low 16, b in high 16
__device__ __forceinline__ unsigned int bfpair(float a, float b) {
    unsigned int ua = __float_as_uint(a);
    unsigned int ub = __float_as_uint(b);
    ua = (ua + 0x7FFFu + ((ua >> 16) & 1u)) >> 16;
    ub = (ub + 0x7FFFu + ((ub >> 16) & 1u)) & 0xFFFF0000u;
    return ub | ua;
}

// ---------- K1: emb16 = bf16(elu(x*w)); zero overflow counter ----------
__global__ void emb_kernel(const float* __restrict__ x,
                           const float* __restrict__ w,
                           unsigned int* __restrict__ emb16,
                           int* __restrict__ ov_cnt,
                           int total4) {
    int i = blockIdx.x * blockDim.x + threadIdx.x;
    if (i == 0) *ov_cnt = 0;
    if (i >= total4) return;
    f32x4 xv = __builtin_nontemporal_load((const f32x4*)x + i);
    float4 wv = ((const float4*)w)[i & (D4 - 1)];
    float4 r;
    r.x = elu1(xv.x * wv.x);
    r.y = elu1(xv.y * wv.y);
    r.z = elu1(xv.z * wv.z);
    r.w = elu1(xv.w * wv.w);
    uint2 o;
    o.x = bfpair(r.x, r.y);
    o.y = bfpair(r.z, r.w);
    ((uint2*)emb16)[i] = o;
}

// ---------- K2: per-chunk LDS bucket sort -> deterministic padded slots ------
__global__ __launch_bounds__(512) void chunk_sort_kernel(
        const int* __restrict__ src, const int* __restrict__ dst,
        int* __restrict__ slots,        // [NCH][NSB][SLOT]
        int* __restrict__ runcount,     // [NCH][NSB]
        int* __restrict__ ov_buf, int* __restrict__ ov_cnt,
        int n_edges, int NSB) {
    __shared__ int hist[256], base[256], cur[256];
    __shared__ int wsum[4];
    __shared__ int stage[CHUNK_E];      // 32 KB
    const int tid = threadIdx.x;
    const int c0  = blockIdx.x * CHUNK_E;
    const int kn  = min(CHUNK_E, n_edges - c0);

    if (tid < 256) hist[tid] = 0;
    __syncthreads();
    for (int k = tid; k < kn; k += 512) {
        int d = dst[c0 + k];
        atomicAdd(&hist[d >> SBSHIFT], 1);
    }
    __syncthreads();
    int h = 0, incl = 0;
    if (tid < 256) {
        h = hist[tid];
        incl = h;
        #pragma unroll
        for (int off = 1; off < 64; off <<= 1) {
            int t = __shfl_up(incl, off, 64);
            if ((tid & 63) >= off) incl += t;
        }
        if ((tid & 63) == 63) wsum[tid >> 6] = incl;
    }
    __syncthreads();
    if (tid < 256) {
        int pre = 0;
        for (int k = 0; k < (tid >> 6); k++) pre += wsum[k];
        int e = pre + incl - h;
        base[tid] = e;
        cur[tid]  = e;
    }
    __syncthreads();
    for (int k = tid; k < kn; k += 512) {
        int d = dst[c0 + k];
        int s = src[c0 + k];
        int pl = ((d & (SBROWS - 1)) << 17) | s;
        int pos = atomicAdd(&cur[d >> SBSHIFT], 1);
        stage[pos] = pl;
    }
    __syncthreads();
    const int wid = tid >> 6, lane = tid & 63;
    const size_t srow = (size_t)blockIdx.x * NSB;
    for (int r = wid; r < NSB; r += 8) {
        int cnt = hist[r];
        int b   = base[r];
        int binned = min(cnt, SLOT);
        size_t gb = (srow + r) * SLOT;
        for (int j = lane; j < binned; j += 64)
            slots[gb + j] = stage[b + j];
        if (lane == 0) runcount[srow + r] = binned;
        for (int j = SLOT + lane; j < cnt; j += 64) {   // rare overflow
            int pl = stage[b + j];
            int pos = atomicAdd(ov_cnt, 1);
            if (pos < OVCAP) {
                ov_buf[2 * pos]     = (r << SBSHIFT) | ((unsigned)pl >> 17);
                ov_buf[2 * pos + 1] = pl & 0x1FFFF;
            }
        }
    }
}

// ---------- K3a: grid-parallel per-sb column sum ----------
__global__ void sbtot_kernel(const int* __restrict__ runcount,
                             int* __restrict__ sbtot, int NSB, int NCH) {
    __shared__ int wsum[4];
    const int s = blockIdx.x;
    const int tid = threadIdx.x;   // 256
    int v = 0;
    for (int c = tid; c < NCH; c += 256) v += runcount[(size_t)c * NSB + s];
    #pragma unroll
    for (int off = 1; off < 64; off <<= 1) v += __shfl_xor(v, off, 64);
    if ((tid & 63) == 0) wsum[tid >> 6] = v;
    __syncthreads();
    if (tid == 0) sbtot[s] = wsum[0] + wsum[1] + wsum[2] + wsum[3];
}

// ---------- K3b: tiny 1-block scan of sbtot -> sb_base ----------
__global__ void sb_scan2_kernel(const int* __restrict__ sbtot,
                                int* __restrict__ sb_base,
                                int* __restrict__ node_off,
                                int NSB, int n_nodes) {
    __shared__ int wsum[4];
    const int tid = threadIdx.x;   // 256 (NSB <= 256)
    int v = (tid < NSB) ? sbtot[tid] : 0;
    int incl = v;
    #pragma unroll
    for (int off = 1; off < 64; off <<= 1) {
        int t = __shfl_up(incl, off, 64);
        if ((tid & 63) >= off) incl += t;
    }
    if ((tid & 63) == 63) wsum[tid >> 6] = incl;
    __syncthreads();
    int pre = 0;
    for (int k = 0; k < (tid >> 6); k++) pre += wsum[k];
    if (tid < NSB) sb_base[tid] = pre + incl - v;
    if (tid == 0) {
        int g = wsum[0] + wsum[1] + wsum[2] + wsum[3];
        sb_base[NSB] = g;
        node_off[n_nodes] = g;
    }
}

// ---------- K4: per-sb LDS counting sort -> sorted2 (coalesced) + node_off ---
__global__ __launch_bounds__(256) void fine_sort_kernel(
        const int* __restrict__ slots,
        const int* __restrict__ runcount,
        const int* __restrict__ sb_base,
        int* __restrict__ sorted2,
        int* __restrict__ node_off,
        int n_nodes, int NSB, int NCH) {
    __shared__ int rc[256];
    __shared__ int counts[SBROWS], cur[SBROWS];
    __shared__ int wsum[4];
    __shared__ int stage_out[STAGE_CAP];   // 34.8 KB
    const int s = blockIdx.x;
    const int tid = threadIdx.x;           // 256
    const int wid = tid >> 6, lane = tid & 63;

    rc[tid] = (tid < NCH) ? runcount[(size_t)tid * NSB + s] : 0;
    for (int i = tid; i < SBROWS; i += 256) counts[i] = 0;
    __syncthreads();
    int rsum = rc[tid];
    #pragma unroll
    for (int off = 1; off < 64; off <<= 1) rsum += __shfl_xor(rsum, off, 64);
    if (lane == 0) wsum[wid] = rsum;
    __syncthreads();
    const int T = wsum[0] + wsum[1] + wsum[2] + wsum[3];
    const bool fast = (T <= STAGE_CAP);
    for (int c = wid; c < NCH; c += 4) {
        int n = rc[c];
        size_t gb = ((size_t)c * NSB + s) * SLOT;
        for (int j = lane; j < n; j += 64)
            atomicAdd(&counts[((unsigned)slots[gb + j]) >> 17], 1);
    }
    __syncthreads();
    int c0v = counts[2 * tid], c1v = counts[2 * tid + 1];
    int pair = c0v + c1v;
    int incl = pair;
    #pragma unroll
    for (int off = 1; off < 64; off <<= 1) {
        int t = __shfl_up(incl, off, 64);
        if ((tid & 63) >= off) incl += t;
    }
    if ((tid & 63) == 63) wsum[tid >> 6] = incl;
    __syncthreads();
    int pre = 0;
    for (int k = 0; k < (tid >> 6); k++) pre += wsum[k];
    const int sbb = sb_base[s];
    int e0 = pre + incl - pair;
    int e1 = e0 + c0v;
    cur[2 * tid]     = fast ? e0 : sbb + e0;
    cur[2 * tid + 1] = fast ? e1 : sbb + e1;
    int g0 = (s << SBSHIFT) + 2 * tid;
    if (g0 < n_nodes)     node_off[g0]     = sbb + e0;
    if (g0 + 1 < n_nodes) node_off[g0 + 1] = sbb + e1;
    __syncthreads();
    for (int c = wid; c < NCH; c += 4) {
        int n = rc[c];
        size_t gb = ((size_t)c * NSB + s) * SLOT;
        for (int j = lane; j < n; j += 64) {
            int pl = slots[gb + j];
            int r = ((unsigned)pl) >> 17;
            int pos = atomicAdd(&cur[r], 1);
            if (fast) stage_out[pos] = pl & 0x1FFFF;
            else      sorted2[pos]   = pl & 0x1FFFF;
        }
    }
    __syncthreads();
    if (fast) {
        for (int i = tid; i < T; i += 256)
            sorted2[sbb + i] = stage_out[i];
    }
}

// ---------- K5: wave per node; 8 groups x 8 lanes; bf16 rows; register accum --
__global__ void gather_sum_kernel(const unsigned int* __restrict__ emb16,
                                  const int* __restrict__ sorted2,
                                  const int* __restrict__ node_off,
                                  float* __restrict__ out, int n_nodes) {
    int wave = (blockIdx.x * blockDim.x + threadIdx.x) >> 6;
    if (wave >= n_nodes) return;
    const int lane = threadIdx.x & 63;
    const int g = lane >> 3;          // 8 edge slots
    const int c = lane & 7;           // 8 int4-chunks per 128B row
    const int beg = node_off[wave], end = node_off[wave + 1];
    const int4* row = (const int4*)emb16;   // 8 int4 per row

    float acc[8] = {0.f, 0.f, 0.f, 0.f, 0.f, 0.f, 0.f, 0.f};
    int e = beg + g;
    for (; e + 8 < end; e += 16) {
        int s0 = __builtin_nontemporal_load(sorted2 + e);
        int s1 = __builtin_nontemporal_load(sorted2 + e + 8);
        int4 u0 = row[s0 * 8 + c];
        int4 u1 = row[s1 * 8 + c];
        acc[0] += __uint_as_float((unsigned)u0.x << 16) + __uint_as_float((unsigned)u1.x << 16);
        acc[1] += __uint_as_float(u0.x & 0xFFFF0000u)   + __uint_as_float(u1.x & 0xFFFF0000u);
        acc[2] += __uint_as_float((unsigned)u0.y << 16) + __uint_as_float((unsigned)u1.y << 16);
        acc[3] += __uint_as_float(u0.y & 0xFFFF0000u)   + __uint_as_float(u1.y & 0xFFFF0000u);
        acc[4] += __uint_as_float((unsigned)u0.z << 16) + __uint_as_float((unsigned)u1.z << 16);
        acc[5] += __uint_as_float(u0.z & 0xFFFF0000u)   + __uint_as_float(u1.z & 0xFFFF0000u);
        acc[6] += __uint_as_float((unsigned)u0.w << 16) + __uint_as_float((unsigned)u1.w << 16);
        acc[7] += __uint_as_float(u0.w & 0xFFFF0000u)   + __uint_as_float(u1.w & 0xFFFF0000u);
    }
    if (e < end) {
        int s0 = __builtin_nontemporal_load(sorted2 + e);
        int4 u0 = row[s0 * 8 + c];
        acc[0] += __uint_as_float((unsigned)u0.x << 16);
        acc[1] += __uint_as_float(u0.x & 0xFFFF0000u);
        acc[2] += __uint_as_float((unsigned)u0.y << 16);
        acc[3] += __uint_as_float(u0.y & 0xFFFF0000u);
        acc[4] += __uint_as_float((unsigned)u0.z << 16);
        acc[5] += __uint_as_float(u0.z & 0xFFFF0000u);
        acc[6] += __uint_as_float((unsigned)u0.w << 16);
        acc[7] += __uint_as_float(u0.w & 0xFFFF0000u);
    }
    #pragma unroll
    for (int off = 8; off <= 32; off <<= 1) {
        #pragma unroll
        for (int k = 0; k < 8; k++) acc[k] += __shfl_xor(acc[k], off, 64);
    }
    if (g == 0) {
        f32x4* out4 = (f32x4*)out;
        f32x4 o0 = {acc[0], acc[1], acc[2], acc[3]};
        f32x4 o1 = {acc[4], acc[5], acc[6], acc[7]};
        __builtin_nontemporal_store(o0, out4 + wave * D4 + c * 2);
        __builtin_nontemporal_store(o1, out4 + wave * D4 + c * 2 + 1);
    }
}

// ---------- K6: apply overflow entries (normally zero) ----------
__global__ void overflow_apply_kernel(const float* __restrict__ x,
                                      const float* __restrict__ w,
                                      const int* __restrict__ ov_buf,
                                      const int* __restrict__ ov_cnt,
                                      float* __restrict__ out) {
    int n = *ov_cnt;
    if (n > OVCAP) n = OVCAP;
    for (int i = blockIdx.x * blockDim.x + threadIdx.x; i < n;
         i += gridDim.x * blockDim.x) {
        int d = ov_buf[2 * i];
        int s = ov_buf[2 * i + 1];
        const float4* x4 = (const float4*)x;
        const float4* w4 = (const float4*)w;
        for (int c = 0; c < D4; c++) {
            float4 xv = x4[s * D4 + c];
            float4 wv = w4[c];
            float* o = out + (size_t)d * D + c * 4;
            unsafeAtomicAdd(o + 0, elu1(xv.x * wv.x));
            unsafeAtomicAdd(o + 1, elu1(xv.y * wv.y));
            unsafeAtomicAdd(o + 2, elu1(xv.z * wv.z));
            unsafeAtomicAdd(o + 3, elu1(xv.w * wv.w));
        }
    }
}

// ---------- Fallback: atomic scatter ----------
__global__ void zero_out_kernel(float* __restrict__ out, int total4) {
    int i = blockIdx.x * blockDim.x + threadIdx.x;
    if (i < total4) ((float4*)out)[i] = make_float4(0.f, 0.f, 0.f, 0.f);
}

__global__ void scatter_fused_kernel(const float* __restrict__ x,
                                     const float* __restrict__ w,
                                     const int* __restrict__ src,
                                     const int* __restrict__ dst,
                                     float* __restrict__ out, int n_edges) {
    int t = blockIdx.x * blockDim.x + threadIdx.x;
    int e = t >> 4;
    int c = t & 15;
    if (e >= n_edges) return;
    int s = src[e];
    int d = dst[e];
    float4 xv = ((const float4*)x)[s * D4 + c];
    float4 wv = ((const float4*)w)[c];
    float* o = out + d * D + c * 4;
    unsafeAtomicAdd(o + 0, elu1(xv.x * wv.x));
    unsafeAtomicAdd(o + 1, elu1(xv.y * wv.y));
    unsafeAtomicAdd(o + 2, elu1(xv.z * wv.z));
    unsafeAtomicAdd(o + 3, elu1(xv.w * wv.w));
}

extern "C" void kernel_launch(void* const* d_in, const int* in_sizes, int n_in,
                              void* d_out, int out_size, void* d_ws, size_t ws_size,
                              hipStream_t stream) {
    const float* x   = (const float*)d_in[0];   // [N, 64] fp32
    const float* w   = (const float*)d_in[1];   // [1, 64] fp32
    const int*   src = (const int*)d_in[2];     // [E] int32
    const int*   dst = (const int*)d_in[3];     // [E] int32
    float* out = (float*)d_out;

    const int n_nodes = in_sizes[0] / D;
    const int n_edges = in_sizes[2];
    const int total4  = n_nodes * D4;
    const int block = 256;

    const int NSB = (n_nodes + SBROWS - 1) >> SBSHIFT;
    const int NCH = (n_edges + CHUNK_E - 1) / CHUNK_E;

    auto align16 = [](size_t v) { return (v + 15) & ~size_t(15); };
    const size_t emb_b      = align16((size_t)n_nodes * D * 2);          // bf16
    const size_t slots_b    = align16((size_t)NCH * NSB * SLOT * 4);
    const size_t runcount_b = align16((size_t)NCH * NSB * 4);
    const size_t sbbase_b   = align16((size_t)(NSB + 1) * 4);
    const size_t sbtot_b    = align16((size_t)NSB * 4);
    const size_t sorted2_b  = align16((size_t)n_edges * 4);
    const size_t nodeoff_b  = align16((size_t)(n_nodes + 1) * 4);
    const size_t ov_b       = align16((size_t)OVCAP * 8);
    const size_t ovcnt_b    = 16;
    const size_t need = emb_b + slots_b + runcount_b + sbbase_b + sbtot_b +
                        sorted2_b + nodeoff_b + ov_b + ovcnt_b;

    if (ws_size >= need && n_nodes <= 131072 && NSB <= 256 && NCH <= 256) {
        char* p = (char*)d_ws;
        unsigned int* emb16 = (unsigned int*)p;  p += emb_b;
        int* slots    = (int*)p;  p += slots_b;
        int* runcount = (int*)p;  p += runcount_b;
        int* sb_base  = (int*)p;  p += sbbase_b;
        int* sbtot    = (int*)p;  p += sbtot_b;
        int* sorted2  = (int*)p;  p += sorted2_b;
        int* node_off = (int*)p;  p += nodeoff_b;
        int* ov_buf   = (int*)p;  p += ov_b;
        int* ov_cnt   = (int*)p;

        emb_kernel<<<(total4 + block - 1) / block, block, 0, stream>>>(
            x, w, emb16, ov_cnt, total4);
        chunk_sort_kernel<<<NCH, 512, 0, stream>>>(
            src, dst, slots, runcount, ov_buf, ov_cnt, n_edges, NSB);
        sbtot_kernel<<<NSB, 256, 0, stream>>>(runcount, sbtot, NSB, NCH);
        sb_scan2_kernel<<<1, 256, 0, stream>>>(sbtot, sb_base, node_off,
                                               NSB, n_nodes);
        fine_sort_kernel<<<NSB, 256, 0, stream>>>(
            slots, runcount, sb_base, sorted2, node_off, n_nodes, NSB, NCH);
        const int wave_blocks = (n_nodes * 64 + block - 1) / block;
        gather_sum_kernel<<<wave_blocks, block, 0, stream>>>(
            emb16, sorted2, node_off, out, n_nodes);
        overflow_apply_kernel<<<32, block, 0, stream>>>(
            x, w, ov_buf, ov_cnt, out);
    } else {
        zero_out_kernel<<<(total4 + block - 1) / block, block, 0, stream>>>(out, total4);
        const int nt = n_edges * 16;
        scatter_fused_kernel<<<(nt + block - 1) / block, block, 0, stream>>>(
            x, w, src, dst, out, n_edges);
    }
}

// Round 9
// 161.808 us; speedup vs baseline: 1.5550x; 1.1587x over previous
//
#include <hip/hip_runtime.h>

#define D 64
#define D4 (D / 4)         // 16 float4 per fp32 row
#define SBSHIFT 9          // 512 nodes per super-bucket
#define SBROWS 512
#define CHUNK_E 8192       // edges per chunk_sort block
#define STAGE_CAP 8704     // fine_sort staging entries (mean ~8163, +6 sigma)
#define NCH_MAX 256
#define NSB_MAX 256

typedef float f32x4 __attribute__((ext_vector_type(4)));

__device__ __forceinline__ float elu1(float z) {
    return z > 0.0f ? z : expm1f(z);
}

// pack two fp32 -> bf16 pair (RNE), a in low 16, b in high 16
__device__ __forceinline__ unsigned int bfpair(float a, float b) {
    unsigned int ua = __float_as_uint(a);
    unsigned int ub = __float_as_uint(b);
    ua = (ua + 0x7FFFu + ((ua >> 16) & 1u)) >> 16;
    ub = (ub + 0x7FFFu + ((ub >> 16) & 1u)) & 0xFFFF0000u;
    return ub | ua;
}

// ---------- K1: emb16 = bf16(elu(x*w)); 32B/lane read, 16B/lane write ----------
__global__ void emb_kernel(const float* __restrict__ x,
                           const float* __restrict__ w,
                           uint4* __restrict__ emb16,
                           int total8) {
    int i = blockIdx.x * blockDim.x + threadIdx.x;
    if (i >= total8) return;
    f32x4 a = __builtin_nontemporal_load((const f32x4*)x + 2 * i);
    f32x4 b = __builtin_nontemporal_load((const f32x4*)x + 2 * i + 1);
    float4 wa = ((const float4*)w)[(2 * i) & 15];
    float4 wb = ((const float4*)w)[(2 * i + 1) & 15];
    uint4 o;
    o.x = bfpair(elu1(a.x * wa.x), elu1(a.y * wa.y));
    o.y = bfpair(elu1(a.z * wa.z), elu1(a.w * wa.w));
    o.z = bfpair(elu1(b.x * wb.x), elu1(b.y * wb.y));
    o.w = bfpair(elu1(b.z * wb.z), elu1(b.w * wb.w));
    emb16[i] = o;
}

// ---------- K2: per-chunk LDS bucket sort -> LINEAR coalesced flush + cbase ----
__global__ __launch_bounds__(512) void chunk_sort_kernel(
        const int* __restrict__ src, const int* __restrict__ dst,
        int* __restrict__ slots_lin,    // [NCH*CHUNK_E], pad-free
        int* __restrict__ cbase,        // [NCH][257] local run offsets
        int n_edges) {
    __shared__ int hist[256], base[256], cur[256];
    __shared__ int wsum[4];
    __shared__ int stage[CHUNK_E];      // 32 KB
    const int tid = threadIdx.x;
    const int lane = tid & 63, wid = tid >> 6;
    const int c0  = blockIdx.x * CHUNK_E;
    const int kn  = min(CHUNK_E, n_edges - c0);
    const int kn4 = kn >> 2;
    const int tail = kn & 3;

    if (tid < 256) hist[tid] = 0;
    __syncthreads();
    // pass 1: histogram by super-bucket (int4 loads)
    const int4* dst4 = (const int4*)(dst + c0);
    for (int k = tid; k < kn4; k += 512) {
        int4 dv = dst4[k];
        atomicAdd(&hist[dv.x >> SBSHIFT], 1);
        atomicAdd(&hist[dv.y >> SBSHIFT], 1);
        atomicAdd(&hist[dv.z >> SBSHIFT], 1);
        atomicAdd(&hist[dv.w >> SBSHIFT], 1);
    }
    if (tid < tail)
        atomicAdd(&hist[dst[c0 + (kn4 << 2) + tid] >> SBSHIFT], 1);
    __syncthreads();
    // exclusive scan of hist[0..256) on waves 0..3
    int h = 0, incl = 0;
    if (tid < 256) {
        h = hist[tid];
        incl = h;
        #pragma unroll
        for (int off = 1; off < 64; off <<= 1) {
            int t = __shfl_up(incl, off, 64);
            if (lane >= off) incl += t;
        }
        if (lane == 63) wsum[wid] = incl;
    }
    __syncthreads();
    if (tid < 256) {
        int pre = 0;
        for (int k = 0; k < wid; k++) pre += wsum[k];
        int e = pre + incl - h;
        base[tid] = e;
        cur[tid]  = e;
    }
    __syncthreads();
    // pass 2: scatter into LDS stage (edges L2-hot from pass 1)
    const int4* src4 = (const int4*)(src + c0);
    for (int k = tid; k < kn4; k += 512) {
        int4 dv = dst4[k];
        int4 sv = src4[k];
        int pos;
        pos = atomicAdd(&cur[dv.x >> SBSHIFT], 1);
        stage[pos] = ((dv.x & (SBROWS - 1)) << 17) | sv.x;
        pos = atomicAdd(&cur[dv.y >> SBSHIFT], 1);
        stage[pos] = ((dv.y & (SBROWS - 1)) << 17) | sv.y;
        pos = atomicAdd(&cur[dv.z >> SBSHIFT], 1);
        stage[pos] = ((dv.z & (SBROWS - 1)) << 17) | sv.z;
        pos = atomicAdd(&cur[dv.w >> SBSHIFT], 1);
        stage[pos] = ((dv.w & (SBROWS - 1)) << 17) | sv.w;
    }
    if (tid < tail) {
        int k = (kn4 << 2) + tid;
        int d = dst[c0 + k], s = src[c0 + k];
        int pos = atomicAdd(&cur[d >> SBSHIFT], 1);
        stage[pos] = ((d & (SBROWS - 1)) << 17) | s;
    }
    __syncthreads();
    // flush: fully coalesced linear copy, no padding, no partial lines
    for (int j = tid; j < kn; j += 512)
        slots_lin[c0 + j] = stage[j];
    if (tid < 256) cbase[blockIdx.x * 257 + tid] = base[tid];
    if (tid == 0)  cbase[blockIdx.x * 257 + 256] = kn;
}

// ---------- K3a: grid-parallel per-sb totals from cbase diffs ----------
__global__ void sbtot_kernel(const int* __restrict__ cbase,
                             int* __restrict__ sbtot, int NSB, int NCH) {
    __shared__ int wsum[4];
    const int s = blockIdx.x;
    const int tid = threadIdx.x;   // 256 (NCH <= 256)
    int v = 0;
    if (tid < NCH)
        v = cbase[tid * 257 + s + 1] - cbase[tid * 257 + s];
    #pragma unroll
    for (int off = 1; off < 64; off <<= 1) v += __shfl_xor(v, off, 64);
    if ((tid & 63) == 0) wsum[tid >> 6] = v;
    __syncthreads();
    if (tid == 0) sbtot[s] = wsum[0] + wsum[1] + wsum[2] + wsum[3];
}

// ---------- K3b: tiny 1-block scan of sbtot -> sb_base[NSB+1] ----------
__global__ void sb_scan2_kernel(const int* __restrict__ sbtot,
                                int* __restrict__ sb_base,
                                int* __restrict__ node_off,
                                int NSB, int n_nodes) {
    __shared__ int wsum[4];
    const int tid = threadIdx.x;   // 256 (NSB <= 256)
    int v = (tid < NSB) ? sbtot[tid] : 0;
    int incl = v;
    #pragma unroll
    for (int off = 1; off < 64; off <<= 1) {
        int t = __shfl_up(incl, off, 64);
        if ((tid & 63) >= off) incl += t;
    }
    if ((tid & 63) == 63) wsum[tid >> 6] = incl;
    __syncthreads();
    int pre = 0;
    for (int k = 0; k < (tid >> 6); k++) pre += wsum[k];
    if (tid < NSB) sb_base[tid] = pre + incl - v;
    if (tid == 0) {
        int g = wsum[0] + wsum[1] + wsum[2] + wsum[3];
        sb_base[NSB] = g;
        node_off[n_nodes] = g;
    }
}

// ---------- K4: per-sb LDS counting sort -> sorted2 (coalesced) + node_off ---
__global__ __launch_bounds__(512) void fine_sort_kernel(
        const int* __restrict__ slots_lin,
        const int* __restrict__ cbase,
        const int* __restrict__ sb_base,
        int* __restrict__ sorted2,
        int* __restrict__ node_off,
        int n_nodes, int NCH) {
    __shared__ int rstart[NCH_MAX], rc[NCH_MAX];
    __shared__ int counts[SBROWS], cur[SBROWS];
    __shared__ int wsum[8];
    __shared__ int stage_out[STAGE_CAP];   // 34.8 KB
    const int s = blockIdx.x;
    const int tid = threadIdx.x;           // 512
    const int wid = tid >> 6, lane = tid & 63;

    if (tid < NCH) {
        int a = cbase[tid * 257 + s];
        int b = cbase[tid * 257 + s + 1];
        rstart[tid] = tid * CHUNK_E + a;
        rc[tid] = b - a;
    }
    counts[tid] = 0;                       // 512 threads cover SBROWS exactly
    __syncthreads();
    const int sbb = sb_base[s];
    const int T   = sb_base[s + 1] - sbb;
    const bool fast = (T <= STAGE_CAP);
    // phase 1: histogram by local node
    for (int c = wid; c < NCH; c += 8) {
        int n = rc[c], st = rstart[c];
        for (int j = lane; j < n; j += 64)
            atomicAdd(&counts[((unsigned)slots_lin[st + j]) >> 17], 1);
    }
    __syncthreads();
    // phase 2: exclusive scan of counts[512], one element per thread
    int v = counts[tid];
    int incl = v;
    #pragma unroll
    for (int off = 1; off < 64; off <<= 1) {
        int t = __shfl_up(incl, off, 64);
        if (lane >= off) incl += t;
    }
    if (lane == 63) wsum[wid] = incl;
    __syncthreads();
    int pre = 0;
    for (int k = 0; k < wid; k++) pre += wsum[k];
    int e0 = pre + incl - v;
    cur[tid] = fast ? e0 : sbb + e0;
    int g0 = (s << SBSHIFT) + tid;
    if (g0 < n_nodes) node_off[g0] = sbb + e0;
    __syncthreads();
    // phase 3: scatter (LDS stage fast path; direct global on skewed sb)
    for (int c = wid; c < NCH; c += 8) {
        int n = rc[c], st = rstart[c];
        for (int j = lane; j < n; j += 64) {
            int pl = slots_lin[st + j];
            int r = ((unsigned)pl) >> 17;
            int pos = atomicAdd(&cur[r], 1);
            if (fast) stage_out[pos] = pl & 0x1FFFF;
            else      sorted2[pos]   = pl & 0x1FFFF;
        }
    }
    __syncthreads();
    // phase 4: coalesced flush
    if (fast) {
        for (int i = tid; i < T; i += 512)
            sorted2[sbb + i] = stage_out[i];
    }
}

// ---------- K5: wave per node; 8 groups x 8 lanes; bf16 rows; register accum --
__global__ void gather_sum_kernel(const unsigned int* __restrict__ emb16,
                                  const int* __restrict__ sorted2,
                                  const int* __restrict__ node_off,
                                  float* __restrict__ out, int n_nodes) {
    int wave = (blockIdx.x * blockDim.x + threadIdx.x) >> 6;
    if (wave >= n_nodes) return;
    const int lane = threadIdx.x & 63;
    const int g = lane >> 3;          // 8 edge slots
    const int c = lane & 7;           // 8 int4-chunks per 128B row
    const int beg = node_off[wave], end = node_off[wave + 1];
    const int4* row = (const int4*)emb16;   // 8 int4 per row

    float acc[8] = {0.f, 0.f, 0.f, 0.f, 0.f, 0.f, 0.f, 0.f};
    int e = beg + g;
    for (; e + 8 < end; e += 16) {
        int s0 = __builtin_nontemporal_load(sorted2 + e);
        int s1 = __builtin_nontemporal_load(sorted2 + e + 8);
        int4 u0 = row[s0 * 8 + c];
        int4 u1 = row[s1 * 8 + c];
        acc[0] += __uint_as_float((unsigned)u0.x << 16) + __uint_as_float((unsigned)u1.x << 16);
        acc[1] += __uint_as_float(u0.x & 0xFFFF0000u)   + __uint_as_float(u1.x & 0xFFFF0000u);
        acc[2] += __uint_as_float((unsigned)u0.y << 16) + __uint_as_float((unsigned)u1.y << 16);
        acc[3] += __uint_as_float(u0.y & 0xFFFF0000u)   + __uint_as_float(u1.y & 0xFFFF0000u);
        acc[4] += __uint_as_float((unsigned)u0.z << 16) + __uint_as_float((unsigned)u1.z << 16);
        acc[5] += __uint_as_float(u0.z & 0xFFFF0000u)   + __uint_as_float(u1.z & 0xFFFF0000u);
        acc[6] += __uint_as_float((unsigned)u0.w << 16) + __uint_as_float((unsigned)u1.w << 16);
        acc[7] += __uint_as_float(u0.w & 0xFFFF0000u)   + __uint_as_float(u1.w & 0xFFFF0000u);
    }
    if (e < end) {
        int s0 = __builtin_nontemporal_load(sorted2 + e);
        int4 u0 = row[s0 * 8 + c];
        acc[0] += __uint_as_float((unsigned)u0.x << 16);
        acc[1] += __uint_as_float(u0.x & 0xFFFF0000u);
        acc[2] += __uint_as_float((unsigned)u0.y << 16);
        acc[3] += __uint_as_float(u0.y & 0xFFFF0000u);
        acc[4] += __uint_as_float((unsigned)u0.z << 16);
        acc[5] += __uint_as_float(u0.z & 0xFFFF0000u);
        acc[6] += __uint_as_float((unsigned)u0.w << 16);
        acc[7] += __uint_as_float(u0.w & 0xFFFF0000u);
    }
    #pragma unroll
    for (int off = 8; off <= 32; off <<= 1) {
        #pragma unroll
        for (int k = 0; k < 8; k++) acc[k] += __shfl_xor(acc[k], off, 64);
    }
    if (g == 0) {
        f32x4* out4 = (f32x4*)out;
        f32x4 o0 = {acc[0], acc[1], acc[2], acc[3]};
        f32x4 o1 = {acc[4], acc[5], acc[6], acc[7]};
        __builtin_nontemporal_store(o0, out4 + wave * D4 + c * 2);
        __builtin_nontemporal_store(o1, out4 + wave * D4 + c * 2 + 1);
    }
}

// ---------- Fallback: atomic scatter ----------
__global__ void zero_out_kernel(float* __restrict__ out, int total4) {
    int i = blockIdx.x * blockDim.x + threadIdx.x;
    if (i < total4) ((float4*)out)[i] = make_float4(0.f, 0.f, 0.f, 0.f);
}

__global__ void scatter_fused_kernel(const float* __restrict__ x,
                                     const float* __restrict__ w,
                                     const int* __restrict__ src,
                                     const int* __restrict__ dst,
                                     float* __restrict__ out, int n_edges) {
    int t = blockIdx.x * blockDim.x + threadIdx.x;
    int e = t >> 4;
    int c = t & 15;
    if (e >= n_edges) return;
    int s = src[e];
    int d = dst[e];
    float4 xv = ((const float4*)x)[s * D4 + c];
    float4 wv = ((const float4*)w)[c];
    float* o = out + d * D + c * 4;
    unsafeAtomicAdd(o + 0, elu1(xv.x * wv.x));
    unsafeAtomicAdd(o + 1, elu1(xv.y * wv.y));
    unsafeAtomicAdd(o + 2, elu1(xv.z * wv.z));
    unsafeAtomicAdd(o + 3, elu1(xv.w * wv.w));
}

extern "C" void kernel_launch(void* const* d_in, const int* in_sizes, int n_in,
                              void* d_out, int out_size, void* d_ws, size_t ws_size,
                              hipStream_t stream) {
    const float* x   = (const float*)d_in[0];   // [N, 64] fp32
    const float* w   = (const float*)d_in[1];   // [1, 64] fp32
    const int*   src = (const int*)d_in[2];     // [E] int32
    const int*   dst = (const int*)d_in[3];     // [E] int32
    float* out = (float*)d_out;

    const int n_nodes = in_sizes[0] / D;
    const int n_edges = in_sizes[2];
    const int total4  = n_nodes * D4;
    const int total8  = n_nodes * 8;
    const int block = 256;

    const int NSB = (n_nodes + SBROWS - 1) >> SBSHIFT;
    const int NCH = (n_edges + CHUNK_E - 1) / CHUNK_E;

    auto align16 = [](size_t v) { return (v + 15) & ~size_t(15); };
    const size_t emb_b      = align16((size_t)n_nodes * D * 2);          // bf16
    const size_t slots_b    = align16((size_t)NCH * CHUNK_E * 4);
    const size_t cbase_b    = align16((size_t)NCH * 257 * 4);
    const size_t sbtot_b    = align16((size_t)NSB * 4);
    const size_t sbbase_b   = align16((size_t)(NSB + 1) * 4);
    const size_t sorted2_b  = align16((size_t)n_edges * 4);
    const size_t nodeoff_b  = align16((size_t)(n_nodes + 1) * 4);
    const size_t need = emb_b + slots_b + cbase_b + sbtot_b + sbbase_b +
                        sorted2_b + nodeoff_b;

    if (ws_size >= need && n_nodes <= 131072 && NSB <= NSB_MAX && NCH <= NCH_MAX) {
        char* p = (char*)d_ws;
        unsigned int* emb16 = (unsigned int*)p;  p += emb_b;
        int* slots_lin = (int*)p;  p += slots_b;
        int* cbase     = (int*)p;  p += cbase_b;
        int* sbtot     = (int*)p;  p += sbtot_b;
        int* sb_base   = (int*)p;  p += sbbase_b;
        int* sorted2   = (int*)p;  p += sorted2_b;
        int* node_off  = (int*)p;

        emb_kernel<<<(total8 + block - 1) / block, block, 0, stream>>>(
            x, w, (uint4*)emb16, total8);
        chunk_sort_kernel<<<NCH, 512, 0, stream>>>(
            src, dst, slots_lin, cbase, n_edges);
        sbtot_kernel<<<NSB, 256, 0, stream>>>(cbase, sbtot, NSB, NCH);
        sb_scan2_kernel<<<1, 256, 0, stream>>>(sbtot, sb_base, node_off,
                                               NSB, n_nodes);
        fine_sort_kernel<<<NSB, 512, 0, stream>>>(
            slots_lin, cbase, sb_base, sorted2, node_off, n_nodes, NCH);
        const int wave_blocks = (n_nodes * 64 + block - 1) / block;
        gather_sum_kernel<<<wave_blocks, block, 0, stream>>>(
            emb16, sorted2, node_off, out, n_nodes);
    } else {
        zero_out_kernel<<<(total4 + block - 1) / block, block, 0, stream>>>(out, total4);
        const int nt = n_edges * 16;
        scatter_fused_kernel<<<(nt + block - 1) / block, block, 0, stream>>>(
            x, w, src, dst, out, n_edges);
    }
}